// Round 6
// baseline (312.685 us; speedup 1.0000x reference)
//
#include <hip/hip_runtime.h>
#include <math.h>

// Problem dims (fixed by reference)
#define BATCH 2048
#define GIN 128
#define GH 128
#define NE 8
#define XIN 512
#define UU 512

typedef __attribute__((ext_vector_type(8))) short short8;   // 8 bf16 in 4 VGPRs
typedef __attribute__((ext_vector_type(4))) float f32x4;

#define AS1 __attribute__((address_space(1)))
#define AS3 __attribute__((address_space(3)))

__device__ inline unsigned short f2bf(float f) {
    unsigned u = __float_as_uint(f);
    u += 0x7fffu + ((u >> 16) & 1u);
    return (unsigned short)(u >> 16);
}

__device__ inline float elu1(float x) { return x > 0.f ? x : (expf(x) - 1.f); }

// ---------------------------------------------------------------------------
// Device-scope grid barrier for a FULLY-RESIDENT grid (512 blocks = 2/CU).
// NOT hipLaunchCooperativeKernel (graph-capture kills it, r3). AGENT-scope
// atomics (per-XCD L2s are not coherent for plain/volatile loads — G16).
// Bounded spin: on pathological non-residency we break -> wrong result ->
// clean test FAIL instead of a hang.
// ---------------------------------------------------------------------------
__device__ __forceinline__ void grid_barrier(unsigned* bar, unsigned nb)
{
    __syncthreads();
    if (threadIdx.x == 0) {
        unsigned* cnt = bar;
        unsigned* gen = bar + 1;
        const unsigned g0 = __hip_atomic_load(gen, __ATOMIC_RELAXED, __HIP_MEMORY_SCOPE_AGENT);
        const unsigned prev = __hip_atomic_fetch_add(cnt, 1u, __ATOMIC_ACQ_REL, __HIP_MEMORY_SCOPE_AGENT);
        if (prev == nb - 1) {
            __hip_atomic_store(cnt, 0u, __ATOMIC_RELAXED, __HIP_MEMORY_SCOPE_AGENT);
            __hip_atomic_fetch_add(gen, 1u, __ATOMIC_RELEASE, __HIP_MEMORY_SCOPE_AGENT);
        } else {
            int spins = 0;
            while (__hip_atomic_load(gen, __ATOMIC_ACQUIRE, __HIP_MEMORY_SCOPE_AGENT) == g0) {
                __builtin_amdgcn_s_sleep(2);
                if (++spins > (1 << 22)) break;   // escape hatch: fail, don't hang
            }
        }
    }
    __threadfence();
    __syncthreads();
}

// ---------------------------------------------------------------------------
// Fused pre-pass: blocks 0..511 run the gating MLP (4 batch rows each);
// blocks 512..7679 convert alpha pools + X fp32->bf16. Block 0 also re-zeroes
// the grid-barrier words (workspace is re-poisoned every iteration).
// ---------------------------------------------------------------------------
__global__ __launch_bounds__(256) void pre_kernel(
    const float* __restrict__ gin, const float* __restrict__ W0, const float* __restrict__ b0,
    const float* __restrict__ W1, const float* __restrict__ b1,
    const float* __restrict__ Wo, const float* __restrict__ bo,
    float* __restrict__ g,
    const float* __restrict__ a0, const float* __restrict__ a1, const float* __restrict__ a2,
    const float* __restrict__ xv, unsigned short* __restrict__ dst,
    unsigned* __restrict__ bar)
{
    __shared__ float xs[4][128];
    __shared__ float hs[4][128];
    __shared__ float ps[2][4][128];
    __shared__ float lp[8][4][8];
    __shared__ float ls[4][8];

    const int t = threadIdx.x;

    if (blockIdx.x == 0 && t == 0) { bar[0] = 0u; bar[1] = 0u; }

    if (blockIdx.x >= 512) {
        // ---- convert part ----
        const long long vi = ((long long)(blockIdx.x - 512) * 256 + t) * 4;
        const int sel = (int)(vi >> 21);         // 0,1,2 = alpha pools; 3 = X
        const float* src = (sel == 0) ? a0 : (sel == 1) ? a1 : (sel == 2) ? a2 : xv;
        float4 v = *(const float4*)(src + (vi & ((1 << 21) - 1)));
        union { unsigned short us[4]; uint2 u2; } p;
        p.us[0] = f2bf(v.x); p.us[1] = f2bf(v.y); p.us[2] = f2bf(v.z); p.us[3] = f2bf(v.w);
        *(uint2*)(dst + vi) = p.u2;
        return;
    }

    // ---- gating part ----
    const int c = t & 127;
    const int h = t >> 7;
    const int row0 = blockIdx.x * 4;

    ((float*)xs)[t]       = gin[row0 * GIN + t];
    ((float*)xs)[t + 256] = gin[row0 * GIN + t + 256];
    __syncthreads();

    {   // layer 0
        float acc0 = 0.f, acc1 = 0.f, acc2 = 0.f, acc3 = 0.f;
        const float* Wc = W0 + c;
        #pragma unroll 8
        for (int i = h * 64; i < h * 64 + 64; ++i) {
            float w = Wc[i * GH];
            acc0 += xs[0][i] * w; acc1 += xs[1][i] * w;
            acc2 += xs[2][i] * w; acc3 += xs[3][i] * w;
        }
        ps[h][0][c] = acc0; ps[h][1][c] = acc1; ps[h][2][c] = acc2; ps[h][3][c] = acc3;
    }
    __syncthreads();
    {
        int o = t, r = o >> 7, cc = o & 127;
        hs[r][cc] = elu1(ps[0][r][cc] + ps[1][r][cc] + b0[cc]);
        o = t + 256; r = o >> 7; cc = o & 127;
        hs[r][cc] = elu1(ps[0][r][cc] + ps[1][r][cc] + b0[cc]);
    }
    __syncthreads();

    {   // layer 1
        float acc0 = 0.f, acc1 = 0.f, acc2 = 0.f, acc3 = 0.f;
        const float* Wc = W1 + c;
        #pragma unroll 8
        for (int i = h * 64; i < h * 64 + 64; ++i) {
            float w = Wc[i * GH];
            acc0 += hs[0][i] * w; acc1 += hs[1][i] * w;
            acc2 += hs[2][i] * w; acc3 += hs[3][i] * w;
        }
        ps[h][0][c] = acc0; ps[h][1][c] = acc1; ps[h][2][c] = acc2; ps[h][3][c] = acc3;
    }
    __syncthreads();
    {
        int o = t, r = o >> 7, cc = o & 127;
        xs[r][cc] = elu1(ps[0][r][cc] + ps[1][r][cc] + b1[cc]);
        o = t + 256; r = o >> 7; cc = o & 127;
        xs[r][cc] = elu1(ps[0][r][cc] + ps[1][r][cc] + b1[cc]);
    }
    __syncthreads();

    {   // output layer, 8-way k-split
        const int e = t & 7, r = (t >> 3) & 3, q = t >> 5;
        float s = 0.f;
        #pragma unroll
        for (int i = q * 16; i < q * 16 + 16; ++i) s += xs[r][i] * Wo[i * NE + e];
        lp[q][r][e] = s;
    }
    __syncthreads();
    if (t < 32) {
        const int r = t >> 3, e = t & 7;
        float s = bo[e];
        #pragma unroll
        for (int q = 0; q < 8; ++q) s += lp[q][r][e];
        ls[r][e] = s;
    }
    __syncthreads();
    if (t < 4) {
        float mx = ls[t][0];
        #pragma unroll
        for (int e = 1; e < 8; ++e) mx = fmaxf(mx, ls[t][e]);
        float s = 0.f, ex[8];
        #pragma unroll
        for (int e = 0; e < 8; ++e) { ex[e] = expf(ls[t][e] - mx); s += ex[e]; }
        float inv = 1.f / s;
        #pragma unroll
        for (int e = 0; e < 8; ++e) g[(row0 + t) * NE + e] = ex[e] * inv;
    }
}

// ---------------------------------------------------------------------------
// Persistent MoE kernel: all 3 layers in ONE dispatch, grid_barrier between.
// Layer body = r5's T3+T4 structure (64Mx32N, 8 experts, BK=32, B-direct,
// triple-buffered A-LDS, counted vmcnt(5), raw s_barrier).
// Grid 512 x 256thr, 47 KB LDS, launch_bounds(256,2) -> 2 blocks/CU, all
// resident (barrier requirement). Single dispatch ~>43us -> finally visible
// in rocprof top-5 with real MfmaUtil/VALUBusy/FETCH counters.
// ---------------------------------------------------------------------------
__global__ __launch_bounds__(256, 2) void moe_persistent_kernel(
    const unsigned short* __restrict__ ab,
    const float* __restrict__ g,
    const float* __restrict__ be0, const float* __restrict__ be1,
    const float* __restrict__ be2,
    unsigned short* __restrict__ Xb0, unsigned short* __restrict__ Xb1,
    float* __restrict__ out,
    unsigned* __restrict__ bar)
{
    constexpr int K = XIN;
    __shared__ unsigned short As[3][64 * 32];   // 12 KB
    __shared__ float red[4][64][32];            // 32 KB
    __shared__ float gs[64][8];                 // 2 KB
    __shared__ float bt[8][32];                 // 1 KB

    const int t = threadIdx.x;
    const int bid = blockIdx.x;
    const int n0 = (bid & 15) * 32;
    const int m0 = (bid >> 4) * 64;
    const int wave = t >> 6, lane = t & 63;
    const int e0 = 2 * wave;
    const int fr = lane & 15;
    const int kq = (lane >> 4) * 8;
    const int slot = t & 3;
    const int arow = t >> 2;
    const int acol = ((slot ^ ((arow >> 1) & 3)) * 8);
    const int cl = lane & 15, rq = lane >> 4;

    // g rows are the same for all three layers: load once.
    ((float2*)gs)[t] = ((const float2*)(g + (size_t)m0 * NE))[t];

    for (int l = 0; l < 3; ++l) {
        const unsigned short* A  = (l == 1) ? Xb1 : Xb0;   // 0:Xb0 1:Xb1 2:Xb0
        unsigned short* Xnext    = (l == 0) ? Xb1 : Xb0;   // unused when last
        const unsigned short* Bw = ab + (size_t)l * (1 << 21);
        const float* beta = (l == 0) ? be0 : (l == 1) ? be1 : be2;
        const int last = (l == 2);

        bt[t >> 5][t & 31] = beta[(t >> 5) * UU + n0 + (t & 31)];

        f32x4 acc[2][4][2] = {};   // [expert-in-pair][m-frag][n-frag]

        const unsigned short* a_src = A + (size_t)(m0 + arow) * K + acol;
        const unsigned short* b_ptr[2][2];
        #pragma unroll
        for (int ep = 0; ep < 2; ++ep)
            #pragma unroll
            for (int j = 0; j < 2; ++j)
                b_ptr[ep][j] = Bw + ((size_t)(e0 + ep) * UU + n0 + j * 16 + fr) * K + kq;

#define STAGE_A(bi, ki)                                                      \
    __builtin_amdgcn_global_load_lds(                                        \
        (const AS1 void*)(a_src + (ki)),                                     \
        (AS3 void*)(&As[bi][t * 8]), 16, 0, 0)

#define LOADB(dst, ki)                                                       \
    do {                                                                     \
        dst[0] = *(const short8*)(b_ptr[0][0] + (ki));                       \
        dst[1] = *(const short8*)(b_ptr[0][1] + (ki));                       \
        dst[2] = *(const short8*)(b_ptr[1][0] + (ki));                       \
        dst[3] = *(const short8*)(b_ptr[1][1] + (ki));                       \
    } while (0)

#define COMPUTE(bi, bf)                                                      \
    do {                                                                     \
        const int fkb_ = (lane >> 4) * 16;                                   \
        const char* Ab_ = (const char*)(&As[bi][0]);                         \
        short8 af_[4];                                                       \
        _Pragma("unroll")                                                    \
        for (int i = 0; i < 4; ++i) {                                        \
            const int row_ = fr + i * 16;                                    \
            af_[i] = *(const short8*)(Ab_ +                                  \
                     ((row_ * 64 + fkb_) ^ (((row_ >> 1) & 3) << 4)));       \
        }                                                                    \
        _Pragma("unroll")                                                    \
        for (int ep = 0; ep < 2; ++ep)                                       \
            _Pragma("unroll")                                                \
            for (int i = 0; i < 4; ++i)                                      \
                _Pragma("unroll")                                            \
                for (int j = 0; j < 2; ++j)                                  \
                    acc[ep][i][j] = __builtin_amdgcn_mfma_f32_16x16x32_bf16( \
                        af_[i], bf[ep * 2 + j], acc[ep][i][j], 0, 0, 0);     \
    } while (0)

        short8 bb0[4], bb1[4], bb2[4];

        // prologue: tiles 0 and 1 in flight; wait tile 0 (5 newer stay out)
        STAGE_A(0, 0);  LOADB(bb0, 0);
        STAGE_A(1, 32); LOADB(bb1, 32);
        asm volatile("s_waitcnt vmcnt(5)" ::: "memory");
        __builtin_amdgcn_s_barrier();

        // steady loop: compute(s) -> issue(s+2) -> wait tile s+1 -> barrier
        #pragma unroll
        for (int s = 0; s < 16; ++s) {
            const int cur = s % 3;
            if (cur == 0)      COMPUTE(0, bb0);
            else if (cur == 1) COMPUTE(1, bb1);
            else               COMPUTE(2, bb2);

            if (s + 2 < 16) {
                const int pre = (s + 2) % 3;
                STAGE_A(pre, (s + 2) * 32);
                if (pre == 0)      LOADB(bb0, (s + 2) * 32);
                else if (pre == 1) LOADB(bb1, (s + 2) * 32);
                else               LOADB(bb2, (s + 2) * 32);
            }
            if (s < 15) {
                if (s + 2 < 16) asm volatile("s_waitcnt vmcnt(5)" ::: "memory");
                else            asm volatile("s_waitcnt vmcnt(0)" ::: "memory");
                __builtin_amdgcn_s_barrier();
            }
        }

        // ---- epilogue: per-wave g/beta blend, cross-wave sum via LDS ----
        #pragma unroll
        for (int i = 0; i < 4; ++i)
            #pragma unroll
            for (int j = 0; j < 2; ++j)
                #pragma unroll
                for (int r = 0; r < 4; ++r) {
                    const int rl = i * 16 + rq * 4 + r;
                    const int co = j * 16 + cl;
                    const float v =
                        gs[rl][e0]     * (acc[0][i][j][r] + bt[e0][co]) +
                        gs[rl][e0 + 1] * (acc[1][i][j][r] + bt[e0 + 1][co]);
                    red[wave][rl][co] = v;
                }
        __syncthreads();

        {
            const int rl = t >> 2;
            const int c0 = (t & 3) * 8;
            float v[8];
            #pragma unroll
            for (int u = 0; u < 8; ++u)
                v[u] = red[0][rl][c0 + u] + red[1][rl][c0 + u] +
                       red[2][rl][c0 + u] + red[3][rl][c0 + u];
            if (last) {
                float4 o0 = {v[0], v[1], v[2], v[3]};
                float4 o1 = {v[4], v[5], v[6], v[7]};
                float* op = out + (size_t)(m0 + rl) * UU + n0 + c0;
                *(float4*)op = o0;
                *(float4*)(op + 4) = o1;
            } else {
                union { unsigned short us[8]; short8 s8; } p;
                #pragma unroll
                for (int u = 0; u < 8; ++u) p.us[u] = f2bf(elu1(v[u]));
                *(short8*)(Xnext + (size_t)(m0 + rl) * UU + n0 + c0) = p.s8;
            }
        }

        if (l < 2) grid_barrier(bar, gridDim.x);
#undef STAGE_A
#undef LOADB
#undef COMPUTE
    }
}

// ---------------------------------------------------------------------------
extern "C" void kernel_launch(void* const* d_in, const int* in_sizes, int n_in,
                              void* d_out, int out_size, void* d_ws, size_t ws_size,
                              hipStream_t stream)
{
    (void)in_sizes; (void)n_in; (void)out_size; (void)ws_size;
    const float* gin = (const float*)d_in[0];
    const float* xin = (const float*)d_in[1];
    const float* W0  = (const float*)d_in[2];
    const float* b0  = (const float*)d_in[3];
    const float* W1  = (const float*)d_in[4];
    const float* b1  = (const float*)d_in[5];
    const float* Wo  = (const float*)d_in[6];
    const float* bo  = (const float*)d_in[7];
    const float* alpha[3] = {(const float*)d_in[8],  (const float*)d_in[10], (const float*)d_in[12]};
    const float* be0 = (const float*)d_in[9];
    const float* be1 = (const float*)d_in[11];
    const float* be2 = (const float*)d_in[13];
    float* out = (float*)d_out;

    // ws layout (~16.9 MB total)
    char* ws = (char*)d_ws;
    float* g = (float*)ws;                                   // 64 KB
    size_t off = 65536;
    unsigned short* ab = (unsigned short*)(ws + off);        // 12.58 MB
    off += (size_t)3 * (1 << 21) * 2;
    unsigned short* Xb0 = (unsigned short*)(ws + off);       // 2.1 MB (contiguous after ab)
    off += (size_t)BATCH * XIN * 2;
    unsigned short* Xb1 = (unsigned short*)(ws + off);       // 2.1 MB
    off += (size_t)BATCH * XIN * 2;
    unsigned* bar = (unsigned*)(ws + off);                   // 8 B barrier state
    off += 64;

    // fused gating + convert (+ barrier zeroing): 512 + 7168 blocks
    pre_kernel<<<512 + 7168, 256, 0, stream>>>(
        gin, W0, b0, W1, b1, Wo, bo, g,
        alpha[0], alpha[1], alpha[2], xin, ab, bar);

    // all three MoE layers in one persistent dispatch
    moe_persistent_kernel<<<512, 256, 0, stream>>>(
        ab, g, be0, be1, be2, Xb0, Xb1, out, bar);
}

// Round 7
// 200.786 us; speedup vs baseline: 1.5573x; 1.5573x over previous
//
#include <hip/hip_runtime.h>
#include <math.h>

// Problem dims (fixed by reference)
#define BATCH 2048
#define GIN 128
#define GH 128
#define NE 8
#define XIN 512
#define UU 512

typedef __attribute__((ext_vector_type(8))) short short8;   // 8 bf16 in 4 VGPRs
typedef __attribute__((ext_vector_type(4))) float f32x4;

__device__ inline unsigned short f2bf(float f) {
    unsigned u = __float_as_uint(f);
    u += 0x7fffu + ((u >> 16) & 1u);
    return (unsigned short)(u >> 16);
}

__device__ inline float elu1(float x) { return x > 0.f ? x : (expf(x) - 1.f); }

// ---------------------------------------------------------------------------
// Fused pre-pass: blocks 0..511 run the gating MLP (4 batch rows each);
// blocks 512..7679 convert alpha pools + X fp32->bf16.
// ---------------------------------------------------------------------------
__global__ __launch_bounds__(256) void pre_kernel(
    const float* __restrict__ gin, const float* __restrict__ W0, const float* __restrict__ b0,
    const float* __restrict__ W1, const float* __restrict__ b1,
    const float* __restrict__ Wo, const float* __restrict__ bo,
    float* __restrict__ g,
    const float* __restrict__ a0, const float* __restrict__ a1, const float* __restrict__ a2,
    const float* __restrict__ xv, unsigned short* __restrict__ dst)
{
    __shared__ float xs[4][128];
    __shared__ float hs[4][128];
    __shared__ float ps[2][4][128];
    __shared__ float lp[8][4][8];
    __shared__ float ls[4][8];

    const int t = threadIdx.x;

    if (blockIdx.x >= 512) {
        // ---- convert part ----
        const long long vi = ((long long)(blockIdx.x - 512) * 256 + t) * 4;
        const int sel = (int)(vi >> 21);         // 0,1,2 = alpha pools; 3 = X
        const float* src = (sel == 0) ? a0 : (sel == 1) ? a1 : (sel == 2) ? a2 : xv;
        float4 v = *(const float4*)(src + (vi & ((1 << 21) - 1)));
        union { unsigned short us[4]; uint2 u2; } p;
        p.us[0] = f2bf(v.x); p.us[1] = f2bf(v.y); p.us[2] = f2bf(v.z); p.us[3] = f2bf(v.w);
        *(uint2*)(dst + vi) = p.u2;
        return;
    }

    // ---- gating part ----
    const int c = t & 127;
    const int h = t >> 7;
    const int row0 = blockIdx.x * 4;

    ((float*)xs)[t]       = gin[row0 * GIN + t];
    ((float*)xs)[t + 256] = gin[row0 * GIN + t + 256];
    __syncthreads();

    {   // layer 0
        float acc0 = 0.f, acc1 = 0.f, acc2 = 0.f, acc3 = 0.f;
        const float* Wc = W0 + c;
        #pragma unroll 8
        for (int i = h * 64; i < h * 64 + 64; ++i) {
            float w = Wc[i * GH];
            acc0 += xs[0][i] * w; acc1 += xs[1][i] * w;
            acc2 += xs[2][i] * w; acc3 += xs[3][i] * w;
        }
        ps[h][0][c] = acc0; ps[h][1][c] = acc1; ps[h][2][c] = acc2; ps[h][3][c] = acc3;
    }
    __syncthreads();
    {
        int o = t, r = o >> 7, cc = o & 127;
        hs[r][cc] = elu1(ps[0][r][cc] + ps[1][r][cc] + b0[cc]);
        o = t + 256; r = o >> 7; cc = o & 127;
        hs[r][cc] = elu1(ps[0][r][cc] + ps[1][r][cc] + b0[cc]);
    }
    __syncthreads();

    {   // layer 1
        float acc0 = 0.f, acc1 = 0.f, acc2 = 0.f, acc3 = 0.f;
        const float* Wc = W1 + c;
        #pragma unroll 8
        for (int i = h * 64; i < h * 64 + 64; ++i) {
            float w = Wc[i * GH];
            acc0 += hs[0][i] * w; acc1 += hs[1][i] * w;
            acc2 += hs[2][i] * w; acc3 += hs[3][i] * w;
        }
        ps[h][0][c] = acc0; ps[h][1][c] = acc1; ps[h][2][c] = acc2; ps[h][3][c] = acc3;
    }
    __syncthreads();
    {
        int o = t, r = o >> 7, cc = o & 127;
        xs[r][cc] = elu1(ps[0][r][cc] + ps[1][r][cc] + b1[cc]);
        o = t + 256; r = o >> 7; cc = o & 127;
        xs[r][cc] = elu1(ps[0][r][cc] + ps[1][r][cc] + b1[cc]);
    }
    __syncthreads();

    {   // output layer, 8-way k-split
        const int e = t & 7, r = (t >> 3) & 3, q = t >> 5;
        float s = 0.f;
        #pragma unroll
        for (int i = q * 16; i < q * 16 + 16; ++i) s += xs[r][i] * Wo[i * NE + e];
        lp[q][r][e] = s;
    }
    __syncthreads();
    if (t < 32) {
        const int r = t >> 3, e = t & 7;
        float s = bo[e];
        #pragma unroll
        for (int q = 0; q < 8; ++q) s += lp[q][r][e];
        ls[r][e] = s;
    }
    __syncthreads();
    if (t < 4) {
        float mx = ls[t][0];
        #pragma unroll
        for (int e = 1; e < 8; ++e) mx = fmaxf(mx, ls[t][e]);
        float s = 0.f, ex[8];
        #pragma unroll
        for (int e = 0; e < 8; ++e) { ex[e] = expf(ls[t][e] - mx); s += ex[e]; }
        float inv = 1.f / s;
        #pragma unroll
        for (int e = 0; e < 8; ++e) g[(row0 + t) * NE + e] = ex[e] * inv;
    }
}

// ---------------------------------------------------------------------------
// One fused MoE layer — BARRIER-FREE K-loop (r6 counters: MfmaUtil 4.6%,
// VALUBusy 2.5%, HBM 2.3%, occ 8 waves/CU -> ~95% stall, pure latency-bound;
// the lockstep barrier/vmcnt cadence at 2 waves/SIMD was the bottleneck).
//  - Block tile 64Mx32N, all 8 experts, BK=32, 16 steps (same math as r5).
//  - NO LDS staging: A and B fragments are per-lane global_load_dwordx4
//    directly into MFMA operand registers (lane's A-frag = 16 contiguous
//    bytes at A[m0+fr+i*16][kq] — identical values the LDS path produced).
//  - Register double-buffer, prefetch distance 2, counted vmcnt(8); all
//    operand deps are register-visible so compiler auto-waitcnt guarantees
//    correctness; NO s_barrier/syncthreads in the loop -> waves free-run,
//    8 independent deep pipelines per CU (~16 loads in flight each).
//  - Only 2 __syncthreads per layer (epilogue cross-wave reduction).
// L2 traffic: A 4x64KB + B 256KB = 512 KB/block-layer (A redundancy is the
// price of wave independence). LDS 35 KB.
// ---------------------------------------------------------------------------
__global__ __launch_bounds__(256) void moe_layer_kernel(
    const unsigned short* __restrict__ A,
    const unsigned short* __restrict__ Bw,
    const float* __restrict__ g,
    const float* __restrict__ beta,
    unsigned short* __restrict__ Xnext,
    float* __restrict__ out, int last)
{
    constexpr int K = XIN;
    __shared__ float red[4][64][32];            // 32 KB
    __shared__ float gs[64][8];                 // 2 KB
    __shared__ float bt[8][32];                 // 1 KB

    const int t = threadIdx.x;
    const int bid = blockIdx.x;
    const int n0 = (bid & 15) * 32;             // bid%8 == n0-pair%8 -> B stays XCD-local
    const int m0 = (bid >> 4) * 64;
    const int wave = t >> 6, lane = t & 63;
    const int e0 = 2 * wave;
    const int fr = lane & 15;
    const int kq = (lane >> 4) * 8;             // k sub-offset within BK=32

    ((float2*)gs)[t] = ((const float2*)(g + (size_t)m0 * NE))[t];
    bt[t >> 5][t & 31] = beta[(t >> 5) * UU + n0 + (t & 31)];
    __syncthreads();                            // gs/bt visible; K-loop has no barriers

    f32x4 acc[2][4][2] = {};   // [expert-in-pair][m-frag][n-frag]

    // per-lane direct operand pointers (k advances via immediate offsets)
    const unsigned short* a_ptr[4];
    #pragma unroll
    for (int i = 0; i < 4; ++i)
        a_ptr[i] = A + (size_t)(m0 + fr + i * 16) * K + kq;
    const unsigned short* b_ptr[4];
    #pragma unroll
    for (int ep = 0; ep < 2; ++ep)
        #pragma unroll
        for (int j = 0; j < 2; ++j)
            b_ptr[ep * 2 + j] = Bw + ((size_t)(e0 + ep) * UU + n0 + j * 16 + fr) * K + kq;

#define LOADT(aa, bb, ki)                                                    \
    do {                                                                     \
        aa[0] = *(const short8*)(a_ptr[0] + (ki));                           \
        aa[1] = *(const short8*)(a_ptr[1] + (ki));                           \
        aa[2] = *(const short8*)(a_ptr[2] + (ki));                           \
        aa[3] = *(const short8*)(a_ptr[3] + (ki));                           \
        bb[0] = *(const short8*)(b_ptr[0] + (ki));                           \
        bb[1] = *(const short8*)(b_ptr[1] + (ki));                           \
        bb[2] = *(const short8*)(b_ptr[2] + (ki));                           \
        bb[3] = *(const short8*)(b_ptr[3] + (ki));                           \
    } while (0)

#define COMPUTE(aa, bb)                                                      \
    do {                                                                     \
        _Pragma("unroll")                                                    \
        for (int ep = 0; ep < 2; ++ep)                                       \
            _Pragma("unroll")                                                \
            for (int i = 0; i < 4; ++i)                                      \
                _Pragma("unroll")                                            \
                for (int j = 0; j < 2; ++j)                                  \
                    acc[ep][i][j] = __builtin_amdgcn_mfma_f32_16x16x32_bf16( \
                        aa[i], bb[ep * 2 + j], acc[ep][i][j], 0, 0, 0);      \
    } while (0)

    short8 aa0[4], aa1[4], bb0[4], bb1[4];

    // prologue: tiles 0,1 in flight (16 VM ops/wave)
    LOADT(aa0, bb0, 0);
    LOADT(aa1, bb1, 32);

    // steady loop: wait(tile s) -> compute(s) -> issue(s+2). No barriers.
    #pragma unroll
    for (int s = 0; s < 16; ++s) {
        if (s < 15) asm volatile("s_waitcnt vmcnt(8)" ::: "memory");
        else        asm volatile("s_waitcnt vmcnt(0)" ::: "memory");
        if (s & 1) {
            COMPUTE(aa1, bb1);
            if (s + 2 < 16) LOADT(aa1, bb1, (s + 2) * 32);
        } else {
            COMPUTE(aa0, bb0);
            if (s + 2 < 16) LOADT(aa0, bb0, (s + 2) * 32);
        }
    }

    // ---- epilogue: per-wave g/beta blend, cross-wave sum via LDS ----
    const int cl = lane & 15, rq = lane >> 4;
    #pragma unroll
    for (int i = 0; i < 4; ++i)
        #pragma unroll
        for (int j = 0; j < 2; ++j)
            #pragma unroll
            for (int r = 0; r < 4; ++r) {
                const int rl = i * 16 + rq * 4 + r;
                const int co = j * 16 + cl;
                const float v =
                    gs[rl][e0]     * (acc[0][i][j][r] + bt[e0][co]) +
                    gs[rl][e0 + 1] * (acc[1][i][j][r] + bt[e0 + 1][co]);
                red[wave][rl][co] = v;
            }
    __syncthreads();

    {
        const int rl = t >> 2;
        const int c0 = (t & 3) * 8;
        float v[8];
        #pragma unroll
        for (int u = 0; u < 8; ++u)
            v[u] = red[0][rl][c0 + u] + red[1][rl][c0 + u] +
                   red[2][rl][c0 + u] + red[3][rl][c0 + u];
        if (last) {
            float4 o0 = {v[0], v[1], v[2], v[3]};
            float4 o1 = {v[4], v[5], v[6], v[7]};
            float* op = out + (size_t)(m0 + rl) * UU + n0 + c0;
            *(float4*)op = o0;
            *(float4*)(op + 4) = o1;
        } else {
            union { unsigned short us[8]; short8 s8; } p;
            #pragma unroll
            for (int u = 0; u < 8; ++u) p.us[u] = f2bf(elu1(v[u]));
            *(short8*)(Xnext + (size_t)(m0 + rl) * UU + n0 + c0) = p.s8;
        }
    }
#undef LOADT
#undef COMPUTE
}

// ---------------------------------------------------------------------------
extern "C" void kernel_launch(void* const* d_in, const int* in_sizes, int n_in,
                              void* d_out, int out_size, void* d_ws, size_t ws_size,
                              hipStream_t stream)
{
    (void)in_sizes; (void)n_in; (void)out_size; (void)ws_size;
    const float* gin = (const float*)d_in[0];
    const float* xin = (const float*)d_in[1];
    const float* W0  = (const float*)d_in[2];
    const float* b0  = (const float*)d_in[3];
    const float* W1  = (const float*)d_in[4];
    const float* b1  = (const float*)d_in[5];
    const float* Wo  = (const float*)d_in[6];
    const float* bo  = (const float*)d_in[7];
    const float* alpha[3] = {(const float*)d_in[8],  (const float*)d_in[10], (const float*)d_in[12]};
    const float* beta[3]  = {(const float*)d_in[9],  (const float*)d_in[11], (const float*)d_in[13]};
    float* out = (float*)d_out;

    // ws layout (~16.8 MB total)
    char* ws = (char*)d_ws;
    float* g = (float*)ws;                                   // 64 KB
    size_t off = 65536;
    unsigned short* ab = (unsigned short*)(ws + off);        // 12.58 MB
    off += (size_t)3 * (1 << 21) * 2;
    unsigned short* Xb0 = (unsigned short*)(ws + off);       // 2.1 MB (contiguous after ab)
    off += (size_t)BATCH * XIN * 2;
    unsigned short* Xb1 = (unsigned short*)(ws + off);       // 2.1 MB
    off += (size_t)BATCH * XIN * 2;

    // fused gating + convert: 512 gating blocks + 7168 convert blocks
    pre_kernel<<<512 + 7168, 256, 0, stream>>>(
        gin, W0, b0, W1, b1, Wo, bo, g,
        alpha[0], alpha[1], alpha[2], xin, ab);

    // ping-pong X buffers
    unsigned short* Xsrc = Xb0;
    unsigned short* Xdst = Xb1;
    for (int l = 0; l < 3; ++l) {
        moe_layer_kernel<<<512, 256, 0, stream>>>(
            Xsrc, ab + (size_t)l * (1 << 21), g, beta[l], Xdst, out, l == 2 ? 1 : 0);
        unsigned short* tmp = Xsrc; Xsrc = Xdst; Xdst = tmp;
    }
}

// Round 8
// 199.676 us; speedup vs baseline: 1.5660x; 1.0056x over previous
//
#include <hip/hip_runtime.h>
#include <math.h>

// Problem dims (fixed by reference)
#define BATCH 2048
#define GIN 128
#define GH 128
#define NE 8
#define XIN 512
#define UU 512

typedef __attribute__((ext_vector_type(8))) short short8;   // 8 bf16 in 4 VGPRs
typedef __attribute__((ext_vector_type(4))) float f32x4;

#define AS1 __attribute__((address_space(1)))
#define AS3 __attribute__((address_space(3)))

__device__ inline unsigned short f2bf(float f) {
    unsigned u = __float_as_uint(f);
    u += 0x7fffu + ((u >> 16) & 1u);
    return (unsigned short)(u >> 16);
}

__device__ inline float elu1(float x) { return x > 0.f ? x : (expf(x) - 1.f); }

// ---------------------------------------------------------------------------
// Fused pre-pass: blocks 0..511 run the gating MLP (4 batch rows each);
// blocks 512..7679 convert alpha pools + X fp32->bf16. (unchanged)
// ---------------------------------------------------------------------------
__global__ __launch_bounds__(256) void pre_kernel(
    const float* __restrict__ gin, const float* __restrict__ W0, const float* __restrict__ b0,
    const float* __restrict__ W1, const float* __restrict__ b1,
    const float* __restrict__ Wo, const float* __restrict__ bo,
    float* __restrict__ g,
    const float* __restrict__ a0, const float* __restrict__ a1, const float* __restrict__ a2,
    const float* __restrict__ xv, unsigned short* __restrict__ dst)
{
    __shared__ float xs[4][128];
    __shared__ float hs[4][128];
    __shared__ float ps[2][4][128];
    __shared__ float lp[8][4][8];
    __shared__ float ls[4][8];

    const int t = threadIdx.x;

    if (blockIdx.x >= 512) {
        // ---- convert part ----
        const long long vi = ((long long)(blockIdx.x - 512) * 256 + t) * 4;
        const int sel = (int)(vi >> 21);         // 0,1,2 = alpha pools; 3 = X
        const float* src = (sel == 0) ? a0 : (sel == 1) ? a1 : (sel == 2) ? a2 : xv;
        float4 v = *(const float4*)(src + (vi & ((1 << 21) - 1)));
        union { unsigned short us[4]; uint2 u2; } p;
        p.us[0] = f2bf(v.x); p.us[1] = f2bf(v.y); p.us[2] = f2bf(v.z); p.us[3] = f2bf(v.w);
        *(uint2*)(dst + vi) = p.u2;
        return;
    }

    // ---- gating part ----
    const int c = t & 127;
    const int h = t >> 7;
    const int row0 = blockIdx.x * 4;

    ((float*)xs)[t]       = gin[row0 * GIN + t];
    ((float*)xs)[t + 256] = gin[row0 * GIN + t + 256];
    __syncthreads();

    {   // layer 0
        float acc0 = 0.f, acc1 = 0.f, acc2 = 0.f, acc3 = 0.f;
        const float* Wc = W0 + c;
        #pragma unroll 8
        for (int i = h * 64; i < h * 64 + 64; ++i) {
            float w = Wc[i * GH];
            acc0 += xs[0][i] * w; acc1 += xs[1][i] * w;
            acc2 += xs[2][i] * w; acc3 += xs[3][i] * w;
        }
        ps[h][0][c] = acc0; ps[h][1][c] = acc1; ps[h][2][c] = acc2; ps[h][3][c] = acc3;
    }
    __syncthreads();
    {
        int o = t, r = o >> 7, cc = o & 127;
        hs[r][cc] = elu1(ps[0][r][cc] + ps[1][r][cc] + b0[cc]);
        o = t + 256; r = o >> 7; cc = o & 127;
        hs[r][cc] = elu1(ps[0][r][cc] + ps[1][r][cc] + b0[cc]);
    }
    __syncthreads();

    {   // layer 1
        float acc0 = 0.f, acc1 = 0.f, acc2 = 0.f, acc3 = 0.f;
        const float* Wc = W1 + c;
        #pragma unroll 8
        for (int i = h * 64; i < h * 64 + 64; ++i) {
            float w = Wc[i * GH];
            acc0 += hs[0][i] * w; acc1 += hs[1][i] * w;
            acc2 += hs[2][i] * w; acc3 += hs[3][i] * w;
        }
        ps[h][0][c] = acc0; ps[h][1][c] = acc1; ps[h][2][c] = acc2; ps[h][3][c] = acc3;
    }
    __syncthreads();
    {
        int o = t, r = o >> 7, cc = o & 127;
        xs[r][cc] = elu1(ps[0][r][cc] + ps[1][r][cc] + b1[cc]);
        o = t + 256; r = o >> 7; cc = o & 127;
        xs[r][cc] = elu1(ps[0][r][cc] + ps[1][r][cc] + b1[cc]);
    }
    __syncthreads();

    {   // output layer, 8-way k-split
        const int e = t & 7, r = (t >> 3) & 3, q = t >> 5;
        float s = 0.f;
        #pragma unroll
        for (int i = q * 16; i < q * 16 + 16; ++i) s += xs[r][i] * Wo[i * NE + e];
        lp[q][r][e] = s;
    }
    __syncthreads();
    if (t < 32) {
        const int r = t >> 3, e = t & 7;
        float s = bo[e];
        #pragma unroll
        for (int q = 0; q < 8; ++q) s += lp[q][r][e];
        ls[r][e] = s;
    }
    __syncthreads();
    if (t < 4) {
        float mx = ls[t][0];
        #pragma unroll
        for (int e = 1; e < 8; ++e) mx = fmaxf(mx, ls[t][e]);
        float s = 0.f, ex[8];
        #pragma unroll
        for (int e = 0; e < 8; ++e) { ex[e] = expf(ls[t][e] - mx); s += ex[e]; }
        float inv = 1.f / s;
        #pragma unroll
        for (int e = 0; e < 8; ++e) g[(row0 + t) * NE + e] = ex[e] * inv;
    }
}

// ---------------------------------------------------------------------------
// One fused MoE layer — OCCUPANCY edition. r6 counters: all pipes <5%, occ
// 24% (8 waves/CU) -> latency-bound with no TLP slack. r7 falsified the
// issue-order theory (barrier-free regressed). This round doubles TLP:
//  - Tile 32Mx32N (was 64x32) -> grid 16x64 = 1024 blocks = 4 blocks/CU.
//  - LDS 22 KB (As 2x2KB dbuf + red 16KB + gs/bt 2KB), launch_bounds(256,4)
//    -> 16 waves/CU (2x every previous round).
//  - Sync structure = r2's best-measured: plain syncthreads double-buffer,
//    STAGE(next)+LOADB(next) issued before COMPUTE(cur).
//  - A via global_load_lds + both-sides swizzle (proven r2); B per-lane
//    direct global->reg (proven r4): af[2], bf[4], 8 MFMA/wave/step.
//  - Wave = expert pair {2w,2w+1} over the full 32x32 tile; cross-wave sum
//    in epilogue via red[].
// bid%8 = n_idx%8 -> all m-blocks sharing an n-tile land on one XCD (B-tile
// L2-resident, 256KB/n-tile, 512KB/XCD).
// ---------------------------------------------------------------------------
__global__ __launch_bounds__(256, 4) void moe_layer_kernel(
    const unsigned short* __restrict__ A,
    const unsigned short* __restrict__ Bw,
    const float* __restrict__ g,
    const float* __restrict__ beta,
    unsigned short* __restrict__ Xnext,
    float* __restrict__ out, int last)
{
    constexpr int K = XIN;
    __shared__ unsigned short As[2][32 * 32];   // 2 x 2 KB
    __shared__ float red[4][32][32];            // 16 KB
    __shared__ float gs[32][8];                 // 1 KB
    __shared__ float bt[8][32];                 // 1 KB

    const int t = threadIdx.x;
    const int n0 = blockIdx.x * 32;
    const int m0 = blockIdx.y * 32;
    const int wave = t >> 6, lane = t & 63;
    const int e0 = 2 * wave;
    const int fr = lane & 15;
    const int kq = (lane >> 4) * 8;             // k sub-offset (elems) within BK=32

    gs[t >> 3][t & 7] = g[(m0 + (t >> 3)) * NE + (t & 7)];
    bt[t >> 5][t & 31] = beta[(t >> 5) * UU + n0 + (t & 31)];

    f32x4 acc[2][2][2] = {};   // [expert-in-pair][m-frag][n-frag]

    // ---- A staging source (threads 0..127; pre-swizzled, linear LDS dest) ----
    const int slot = t & 3;                 // 16B slot within 64B LDS row
    const int arow = (t >> 2) & 31;         // LDS row (t<128 -> 0..31)
    const int acol = ((slot ^ ((arow >> 1) & 3)) * 8);
    const unsigned short* a_src = A + (size_t)(m0 + arow) * K + acol;

    // ---- B per-lane direct sources (4 frag rows per wave) ----
    const unsigned short* b_ptr[4];
    #pragma unroll
    for (int ep = 0; ep < 2; ++ep)
        #pragma unroll
        for (int j = 0; j < 2; ++j)
            b_ptr[ep * 2 + j] = Bw + ((size_t)(e0 + ep) * UU + n0 + j * 16 + fr) * K + kq;

#define STAGE_A(bi, ki)                                                      \
    do {                                                                     \
        if (t < 128)                                                         \
            __builtin_amdgcn_global_load_lds(                                \
                (const AS1 void*)(a_src + (ki)),                             \
                (AS3 void*)(&As[bi][t * 8]), 16, 0, 0);                      \
    } while (0)

#define LOADB(dst, ki)                                                       \
    do {                                                                     \
        dst[0] = *(const short8*)(b_ptr[0] + (ki));                          \
        dst[1] = *(const short8*)(b_ptr[1] + (ki));                          \
        dst[2] = *(const short8*)(b_ptr[2] + (ki));                          \
        dst[3] = *(const short8*)(b_ptr[3] + (ki));                          \
    } while (0)

#define COMPUTE(bi, bf)                                                      \
    do {                                                                     \
        const int fkb_ = (lane >> 4) * 16;                                   \
        const char* Ab_ = (const char*)(&As[bi][0]);                         \
        short8 af_[2];                                                       \
        _Pragma("unroll")                                                    \
        for (int i = 0; i < 2; ++i) {                                        \
            const int row_ = fr + i * 16;                                    \
            af_[i] = *(const short8*)(Ab_ +                                  \
                     ((row_ * 64 + fkb_) ^ (((row_ >> 1) & 3) << 4)));       \
        }                                                                    \
        _Pragma("unroll")                                                    \
        for (int ep = 0; ep < 2; ++ep)                                       \
            _Pragma("unroll")                                                \
            for (int i = 0; i < 2; ++i)                                      \
                _Pragma("unroll")                                            \
                for (int j = 0; j < 2; ++j)                                  \
                    acc[ep][i][j] = __builtin_amdgcn_mfma_f32_16x16x32_bf16( \
                        af_[i], bf[ep * 2 + j], acc[ep][i][j], 0, 0, 0);     \
    } while (0)

    short8 bb0[4], bb1[4];

    // prologue: tile 0 (A -> LDS buf0, B -> bb0)
    STAGE_A(0, 0);
    LOADB(bb0, 0);
    __syncthreads();

    // main loop (r2 structure): stage(next) -> compute(cur) -> barrier
    #pragma unroll
    for (int s = 0; s < 16; ++s) {
        if (s < 15) {
            STAGE_A((s + 1) & 1, (s + 1) * 32);
            if (s & 1) LOADB(bb0, (s + 1) * 32);
            else       LOADB(bb1, (s + 1) * 32);
        }
        if (s & 1) COMPUTE(1, bb1);
        else       COMPUTE(0, bb0);
        __syncthreads();
    }

    // ---- epilogue: per-wave g/beta blend, cross-wave sum via LDS ----
    const int cl = lane & 15, rq = lane >> 4;
    #pragma unroll
    for (int i = 0; i < 2; ++i)
        #pragma unroll
        for (int j = 0; j < 2; ++j)
            #pragma unroll
            for (int r = 0; r < 4; ++r) {
                const int rl = i * 16 + rq * 4 + r;     // row in tile (0..31)
                const int co = j * 16 + cl;             // col in tile (0..31)
                const float v =
                    gs[rl][e0]     * (acc[0][i][j][r] + bt[e0][co]) +
                    gs[rl][e0 + 1] * (acc[1][i][j][r] + bt[e0 + 1][co]);
                red[wave][rl][co] = v;
            }
    __syncthreads();

    {
        const int rl = t >> 3;              // 0..31
        const int c0 = (t & 7) * 4;         // 0..28
        float v[4];
        #pragma unroll
        for (int u = 0; u < 4; ++u)
            v[u] = red[0][rl][c0 + u] + red[1][rl][c0 + u] +
                   red[2][rl][c0 + u] + red[3][rl][c0 + u];
        if (last) {
            float4 o = {v[0], v[1], v[2], v[3]};
            *(float4*)(out + (size_t)(m0 + rl) * UU + n0 + c0) = o;
        } else {
            union { unsigned short us[4]; uint2 u2; } p;
            #pragma unroll
            for (int u = 0; u < 4; ++u) p.us[u] = f2bf(elu1(v[u]));
            *(uint2*)(Xnext + (size_t)(m0 + rl) * UU + n0 + c0) = p.u2;
        }
    }
#undef STAGE_A
#undef LOADB
#undef COMPUTE
}

// ---------------------------------------------------------------------------
extern "C" void kernel_launch(void* const* d_in, const int* in_sizes, int n_in,
                              void* d_out, int out_size, void* d_ws, size_t ws_size,
                              hipStream_t stream)
{
    (void)in_sizes; (void)n_in; (void)out_size; (void)ws_size;
    const float* gin = (const float*)d_in[0];
    const float* xin = (const float*)d_in[1];
    const float* W0  = (const float*)d_in[2];
    const float* b0  = (const float*)d_in[3];
    const float* W1  = (const float*)d_in[4];
    const float* b1  = (const float*)d_in[5];
    const float* Wo  = (const float*)d_in[6];
    const float* bo  = (const float*)d_in[7];
    const float* alpha[3] = {(const float*)d_in[8],  (const float*)d_in[10], (const float*)d_in[12]};
    const float* beta[3]  = {(const float*)d_in[9],  (const float*)d_in[11], (const float*)d_in[13]};
    float* out = (float*)d_out;

    // ws layout (~16.8 MB total)
    char* ws = (char*)d_ws;
    float* g = (float*)ws;                                   // 64 KB
    size_t off = 65536;
    unsigned short* ab = (unsigned short*)(ws + off);        // 12.58 MB
    off += (size_t)3 * (1 << 21) * 2;
    unsigned short* Xb0 = (unsigned short*)(ws + off);       // 2.1 MB (contiguous after ab)
    off += (size_t)BATCH * XIN * 2;
    unsigned short* Xb1 = (unsigned short*)(ws + off);       // 2.1 MB
    off += (size_t)BATCH * XIN * 2;

    // fused gating + convert: 512 gating blocks + 7168 convert blocks
    pre_kernel<<<512 + 7168, 256, 0, stream>>>(
        gin, W0, b0, W1, b1, Wo, bo, g,
        alpha[0], alpha[1], alpha[2], xin, ab);

    // ping-pong X buffers
    unsigned short* Xsrc = Xb0;
    unsigned short* Xdst = Xb1;
    for (int l = 0; l < 3; ++l) {
        moe_layer_kernel<<<dim3(16, 64), 256, 0, stream>>>(
            Xsrc, ab + (size_t)l * (1 << 21), g, beta[l], Xdst, out, l == 2 ? 1 : 0);
        unsigned short* tmp = Xsrc; Xsrc = Xdst; Xdst = tmp;
    }
}

// Round 9
// 162.284 us; speedup vs baseline: 1.9268x; 1.2304x over previous
//
#include <hip/hip_runtime.h>
#include <math.h>

// Problem dims (fixed by reference)
#define BATCH 2048
#define GIN 128
#define GH 128
#define NE 8
#define XIN 512
#define UU 512

typedef __attribute__((ext_vector_type(8))) short short8;   // 8 bf16 in 4 VGPRs
typedef __attribute__((ext_vector_type(4))) float f32x4;

#define AS1 __attribute__((address_space(1)))
#define AS3 __attribute__((address_space(3)))

__device__ inline unsigned short f2bf(float f) {
    unsigned u = __float_as_uint(f);
    u += 0x7fffu + ((u >> 16) & 1u);
    return (unsigned short)(u >> 16);
}

__device__ inline float elu1(float x) { return x > 0.f ? x : (expf(x) - 1.f); }

// ---------------------------------------------------------------------------
// Fused pre-pass: blocks 0..511 run the gating MLP (4 batch rows each);
// blocks 512..7679 convert alpha pools + X fp32->bf16. (unchanged)
// ---------------------------------------------------------------------------
__global__ __launch_bounds__(256) void pre_kernel(
    const float* __restrict__ gin, const float* __restrict__ W0, const float* __restrict__ b0,
    const float* __restrict__ W1, const float* __restrict__ b1,
    const float* __restrict__ Wo, const float* __restrict__ bo,
    float* __restrict__ g,
    const float* __restrict__ a0, const float* __restrict__ a1, const float* __restrict__ a2,
    const float* __restrict__ xv, unsigned short* __restrict__ dst)
{
    __shared__ float xs[4][128];
    __shared__ float hs[4][128];
    __shared__ float ps[2][4][128];
    __shared__ float lp[8][4][8];
    __shared__ float ls[4][8];

    const int t = threadIdx.x;

    if (blockIdx.x >= 512) {
        // ---- convert part ----
        const long long vi = ((long long)(blockIdx.x - 512) * 256 + t) * 4;
        const int sel = (int)(vi >> 21);         // 0,1,2 = alpha pools; 3 = X
        const float* src = (sel == 0) ? a0 : (sel == 1) ? a1 : (sel == 2) ? a2 : xv;
        float4 v = *(const float4*)(src + (vi & ((1 << 21) - 1)));
        union { unsigned short us[4]; uint2 u2; } p;
        p.us[0] = f2bf(v.x); p.us[1] = f2bf(v.y); p.us[2] = f2bf(v.z); p.us[3] = f2bf(v.w);
        *(uint2*)(dst + vi) = p.u2;
        return;
    }

    // ---- gating part ----
    const int c = t & 127;
    const int h = t >> 7;
    const int row0 = blockIdx.x * 4;

    ((float*)xs)[t]       = gin[row0 * GIN + t];
    ((float*)xs)[t + 256] = gin[row0 * GIN + t + 256];
    __syncthreads();

    {   // layer 0
        float acc0 = 0.f, acc1 = 0.f, acc2 = 0.f, acc3 = 0.f;
        const float* Wc = W0 + c;
        #pragma unroll 8
        for (int i = h * 64; i < h * 64 + 64; ++i) {
            float w = Wc[i * GH];
            acc0 += xs[0][i] * w; acc1 += xs[1][i] * w;
            acc2 += xs[2][i] * w; acc3 += xs[3][i] * w;
        }
        ps[h][0][c] = acc0; ps[h][1][c] = acc1; ps[h][2][c] = acc2; ps[h][3][c] = acc3;
    }
    __syncthreads();
    {
        int o = t, r = o >> 7, cc = o & 127;
        hs[r][cc] = elu1(ps[0][r][cc] + ps[1][r][cc] + b0[cc]);
        o = t + 256; r = o >> 7; cc = o & 127;
        hs[r][cc] = elu1(ps[0][r][cc] + ps[1][r][cc] + b0[cc]);
    }
    __syncthreads();

    {   // layer 1
        float acc0 = 0.f, acc1 = 0.f, acc2 = 0.f, acc3 = 0.f;
        const float* Wc = W1 + c;
        #pragma unroll 8
        for (int i = h * 64; i < h * 64 + 64; ++i) {
            float w = Wc[i * GH];
            acc0 += hs[0][i] * w; acc1 += hs[1][i] * w;
            acc2 += hs[2][i] * w; acc3 += hs[3][i] * w;
        }
        ps[h][0][c] = acc0; ps[h][1][c] = acc1; ps[h][2][c] = acc2; ps[h][3][c] = acc3;
    }
    __syncthreads();
    {
        int o = t, r = o >> 7, cc = o & 127;
        xs[r][cc] = elu1(ps[0][r][cc] + ps[1][r][cc] + b1[cc]);
        o = t + 256; r = o >> 7; cc = o & 127;
        xs[r][cc] = elu1(ps[0][r][cc] + ps[1][r][cc] + b1[cc]);
    }
    __syncthreads();

    {   // output layer, 8-way k-split
        const int e = t & 7, r = (t >> 3) & 3, q = t >> 5;
        float s = 0.f;
        #pragma unroll
        for (int i = q * 16; i < q * 16 + 16; ++i) s += xs[r][i] * Wo[i * NE + e];
        lp[q][r][e] = s;
    }
    __syncthreads();
    if (t < 32) {
        const int r = t >> 3, e = t & 7;
        float s = bo[e];
        #pragma unroll
        for (int q = 0; q < 8; ++q) s += lp[q][r][e];
        ls[r][e] = s;
    }
    __syncthreads();
    if (t < 4) {
        float mx = ls[t][0];
        #pragma unroll
        for (int e = 1; e < 8; ++e) mx = fmaxf(mx, ls[t][e]);
        float s = 0.f, ex[8];
        #pragma unroll
        for (int e = 0; e < 8; ++e) { ex[e] = expf(ls[t][e] - mx); s += ex[e]; }
        float inv = 1.f / s;
        #pragma unroll
        for (int e = 0; e < 8; ++e) g[(row0 + t) * NE + e] = ex[e] * inv;
    }
}

// ---------------------------------------------------------------------------
// One fused MoE layer — SINGLE-STAGE edition (BK = K = 512).
// Diagnosis across r2..r8 + r6 counters (all pipes <5%, ~95% stall): the
// binding cost is a fixed ~1.5-2.7k cycle overhead PER barrier-synced K-step
// (m233/m97), and all prior variants ran 16 thin steps. This version has
// exactly ONE staged step:
//  - A-tile 64x512 (64 KB) -> LDS once via global_load_lds (16/thread),
//    both-sides swizzle byte^=((row&7)<<4); ONE vmcnt+barrier to cover it.
//    (B's kk0/kk1 prefetch is issued first; vmcnt(8) leaves it in flight.)
//  - B: per-lane direct global->reg, 3-slot register pipeline (12 loads in
//    flight, counted vmcnt, full unroll => static slots). Zero barriers.
//  - Per wave: 256 MFMA between barriers (was 16). Barrier-crossings per
//    layer: 3 (stage, pre-red, post-red) vs 17 before.
//  - Wave = expert pair {2w,2w+1} over full 64x32 tile; epilogue red[]
//    ALIASED over dead As. LDS 67 KB -> 2 blocks/CU. VGPR ~150.
// Grid dim3(16,32)=512; linear bid%8 = n-tile%8 -> B (256KB/n-tile) stays
// XCD-L2-resident (512KB/XCD/layer).
// ---------------------------------------------------------------------------
__global__ __launch_bounds__(256, 2) void moe_layer_kernel(
    const unsigned short* __restrict__ A,
    const unsigned short* __restrict__ Bw,
    const float* __restrict__ g,
    const float* __restrict__ beta,
    unsigned short* __restrict__ Xnext,
    float* __restrict__ out, int last)
{
    constexpr int K = XIN;
    __shared__ unsigned short As[64 * 512];     // 64 KB (red[] aliases later)
    __shared__ float gs[64][8];                 // 2 KB
    __shared__ float bt[8][32];                 // 1 KB

    const int t = threadIdx.x;
    const int n0 = blockIdx.x * 32;
    const int m0 = blockIdx.y * 64;
    const int wave = t >> 6, lane = t & 63;
    const int e0 = 2 * wave;
    const int fr = lane & 15;
    const int qb = (lane >> 4) * 16;            // 16B k-slot within a 64B kk-chunk

    ((float2*)gs)[t] = ((const float2*)(g + (size_t)m0 * NE))[t];
    bt[t >> 5][t & 31] = beta[(t >> 5) * UU + n0 + (t & 31)];

    f32x4 acc[2][4][2] = {};   // [expert-in-pair][m-frag][n-frag]

    // ---- B per-lane direct sources (4 frag rows per wave; row = 1KB) ----
    const unsigned short* b_ptr[4];
    #pragma unroll
    for (int ep = 0; ep < 2; ++ep)
        #pragma unroll
        for (int j = 0; j < 2; ++j)
            b_ptr[ep * 2 + j] =
                Bw + ((size_t)(e0 + ep) * UU + n0 + j * 16 + fr) * K + (lane >> 4) * 8;

    short8 bb[3][4];   // 3-slot rotating pipeline (48 VGPR)

#define LOADB(slot, kk)                                                      \
    do {                                                                     \
        bb[slot][0] = *(const short8*)(b_ptr[0] + (kk) * 32);                \
        bb[slot][1] = *(const short8*)(b_ptr[1] + (kk) * 32);                \
        bb[slot][2] = *(const short8*)(b_ptr[2] + (kk) * 32);                \
        bb[slot][3] = *(const short8*)(b_ptr[3] + (kk) * 32);                \
    } while (0)

    // prologue: B kk=0,1 in flight FIRST (they ride out the stage wait)
    LOADB(0, 0);
    LOADB(1, 1);

    // ---- stage the whole A-tile (64 rows x 512 cols, swizzled) ----
    // iteration it: wave w stages row it*4+w, lane covers col-bytes lane*16.
    #pragma unroll
    for (int it = 0; it < 16; ++it) {
        const int ldsb = it * 4096 + t * 16;
        const int row  = ldsb >> 10;
        const int colb = (ldsb & 1023) ^ ((row & 7) << 4);   // pre-swizzled src
        __builtin_amdgcn_global_load_lds(
            (const AS1 void*)(A + (size_t)(m0 + row) * K + (colb >> 1)),
            (AS3 void*)((char*)As + ldsb), 16, 0, 0);
    }
    // out/wave = 8 B-loads + 16 stage; vmcnt(8) => stage complete, B flying
    asm volatile("s_waitcnt vmcnt(8)" ::: "memory");
    __builtin_amdgcn_s_barrier();

    // ---- single fat compute phase: 16 kk, 256 MFMA/wave, no barriers ----
    #pragma unroll
    for (int kk = 0; kk < 16; ++kk) {
        if (kk + 2 < 16) LOADB((kk + 2) % 3, kk + 2);
        if (kk <= 13)      asm volatile("s_waitcnt vmcnt(8)" ::: "memory");
        else if (kk == 14) asm volatile("s_waitcnt vmcnt(4)" ::: "memory");
        else               asm volatile("s_waitcnt vmcnt(0)" ::: "memory");

        short8 af[4];
        #pragma unroll
        for (int i = 0; i < 4; ++i) {
            const int row = fr + i * 16;
            af[i] = *(const short8*)((const char*)As +
                    ((row * 1024 + kk * 64 + qb) ^ ((fr & 7) << 4)));
        }
        const int s = kk % 3;
        #pragma unroll
        for (int ep = 0; ep < 2; ++ep)
            #pragma unroll
            for (int i = 0; i < 4; ++i)
                #pragma unroll
                for (int j = 0; j < 2; ++j)
                    acc[ep][i][j] = __builtin_amdgcn_mfma_f32_16x16x32_bf16(
                        af[i], bb[s][ep * 2 + j], acc[ep][i][j], 0, 0, 0);
    }

    // ---- epilogue: blend + cross-wave sum via red[] aliased over As ----
    __syncthreads();                       // all af reads done -> safe to alias
    float* red = (float*)As;               // 4 waves x 64 x 32 f32 = 32 KB

    const int cl = lane & 15, rq = lane >> 4;
    #pragma unroll
    for (int i = 0; i < 4; ++i)
        #pragma unroll
        for (int j = 0; j < 2; ++j)
            #pragma unroll
            for (int r = 0; r < 4; ++r) {
                const int rl = i * 16 + rq * 4 + r;
                const int co = j * 16 + cl;
                const float v =
                    gs[rl][e0]     * (acc[0][i][j][r] + bt[e0][co]) +
                    gs[rl][e0 + 1] * (acc[1][i][j][r] + bt[e0 + 1][co]);
                red[wave * 2048 + rl * 32 + co] = v;
            }
    __syncthreads();

    {
        const int rl = t >> 2;
        const int c0 = (t & 3) * 8;
        float v[8];
        #pragma unroll
        for (int u = 0; u < 8; ++u) {
            const int idx = rl * 32 + c0 + u;
            v[u] = red[idx] + red[2048 + idx] + red[4096 + idx] + red[6144 + idx];
        }
        if (last) {
            float4 o0 = {v[0], v[1], v[2], v[3]};
            float4 o1 = {v[4], v[5], v[6], v[7]};
            float* op = out + (size_t)(m0 + rl) * UU + n0 + c0;
            *(float4*)op = o0;
            *(float4*)(op + 4) = o1;
        } else {
            union { unsigned short us[8]; short8 s8; } p;
            #pragma unroll
            for (int u = 0; u < 8; ++u) p.us[u] = f2bf(elu1(v[u]));
            *(short8*)(Xnext + (size_t)(m0 + rl) * UU + n0 + c0) = p.s8;
        }
    }
#undef LOADB
}

// ---------------------------------------------------------------------------
extern "C" void kernel_launch(void* const* d_in, const int* in_sizes, int n_in,
                              void* d_out, int out_size, void* d_ws, size_t ws_size,
                              hipStream_t stream)
{
    (void)in_sizes; (void)n_in; (void)out_size; (void)ws_size;
    const float* gin = (const float*)d_in[0];
    const float* xin = (const float*)d_in[1];
    const float* W0  = (const float*)d_in[2];
    const float* b0  = (const float*)d_in[3];
    const float* W1  = (const float*)d_in[4];
    const float* b1  = (const float*)d_in[5];
    const float* Wo  = (const float*)d_in[6];
    const float* bo  = (const float*)d_in[7];
    const float* alpha[3] = {(const float*)d_in[8],  (const float*)d_in[10], (const float*)d_in[12]};
    const float* beta[3]  = {(const float*)d_in[9],  (const float*)d_in[11], (const float*)d_in[13]};
    float* out = (float*)d_out;

    // ws layout (~16.8 MB total)
    char* ws = (char*)d_ws;
    float* g = (float*)ws;                                   // 64 KB
    size_t off = 65536;
    unsigned short* ab = (unsigned short*)(ws + off);        // 12.58 MB
    off += (size_t)3 * (1 << 21) * 2;
    unsigned short* Xb0 = (unsigned short*)(ws + off);       // 2.1 MB (contiguous after ab)
    off += (size_t)BATCH * XIN * 2;
    unsigned short* Xb1 = (unsigned short*)(ws + off);       // 2.1 MB
    off += (size_t)BATCH * XIN * 2;

    // fused gating + convert: 512 gating blocks + 7168 convert blocks
    pre_kernel<<<512 + 7168, 256, 0, stream>>>(
        gin, W0, b0, W1, b1, Wo, bo, g,
        alpha[0], alpha[1], alpha[2], xin, ab);

    // ping-pong X buffers
    unsigned short* Xsrc = Xb0;
    unsigned short* Xdst = Xb1;
    for (int l = 0; l < 3; ++l) {
        moe_layer_kernel<<<dim3(16, 32), 256, 0, stream>>>(
            Xsrc, ab + (size_t)l * (1 << 21), g, beta[l], Xdst, out, l == 2 ? 1 : 0);
        unsigned short* tmp = Xsrc; Xsrc = Xdst; Xdst = tmp;
    }
}